// Round 2
// baseline (286.668 us; speedup 1.0000x reference)
//
#include <hip/hip_runtime.h>
#include <hip/hip_bf16.h>

// LoKr: out = x @ kron(w1, a@b).T * S, factored into 3 small GEMMs.
// x: [8192, 4096] fp32 (8192 positions), w1: [8,8], a: [512,64], b: [64,512]
// out[p, oi*512+ok] = sum_r a[ok,r] * v[p,oi,r]
//   v[p,oi,r] = sum_ij (S*w1[oi,ij]) * t[p,ij,r]
//   t[p,ij,r] = sum_il x[p, ij*512+il] * b[r,il]
//
// R1->R2: latency-bound fix. Block of 4 waves handles 4 positions; wave pair
// (pair, rh) splits the r dimension (rh*32..+32) in stage 1/2 and the n-tile
// range (rh*16..+16) in stage 3. Grid 1024->2048 blocks = 8192 waves = 100%
// machine capacity; __launch_bounds__(256,8) pins VGPR<=64 for 8 waves/SIMD.

typedef __attribute__((ext_vector_type(4))) float f32x4;
typedef __attribute__((ext_vector_type(8))) short s16x8;

__device__ inline unsigned short f2bf(float f) {
    unsigned u = __float_as_uint(f);
    u += 0x7FFF + ((u >> 16) & 1);   // round-to-nearest-even
    return (unsigned short)(u >> 16);
}

// Precompute: b -> bf16 [64][512] (row=r, col=il), a -> bf16 [512][64]
// (row=ok, col=r), w1s = w1 * (1/64). Into d_ws (re-poisoned each call).
__global__ void lokr_pre(const float* __restrict__ w1,
                         const float* __restrict__ a,
                         const float* __restrict__ b,
                         unsigned short* __restrict__ b_bf,
                         unsigned short* __restrict__ a_bf,
                         float* __restrict__ w1s) {
    int i = blockIdx.x * 256 + threadIdx.x;
    if (i < 32768) {
        b_bf[i] = f2bf(b[i]);
        a_bf[i] = f2bf(a[i]);
    }
    if (i < 64) w1s[i] = w1[i] * (1.0f / 64.0f);
}

__global__ __launch_bounds__(256, 8) void lokr_main(
    const float* __restrict__ x,
    const unsigned short* __restrict__ b_bf,
    const unsigned short* __restrict__ a_bf,
    const float* __restrict__ w1s,
    float* __restrict__ out)
{
    __shared__ float w1_s[64];
    // v per pair: 16 rows (lp*8+oi) x 64 r, bf16; row stride 72 ushorts
    // (144 B) keeps ds_read_b128 16B-aligned; row-conflicts are only 2-way
    // (free on gfx950).
    __shared__ __attribute__((aligned(16))) unsigned short v_lds[2][16 * 72];

    const int tid = threadIdx.x;
    if (tid < 64) w1_s[tid] = w1s[tid];
    __syncthreads();

    const int wave = tid >> 6;
    const int lane = tid & 63;
    const int col  = lane & 15;   // MFMA: A row / B col / C col
    const int quad = lane >> 4;
    const int pair = wave >> 1;   // which position-pair this wave serves
    const int rh   = wave & 1;    // which r-half (stage 1/2) / n-half (stage 3)

    const long gp = ((long)blockIdx.x * 2 + pair) * 2;  // 2 positions per pair

    // ---------- stage 1: t[16][r-half 32] = X_rows[16 x 512] @ b^T ----------
    // A[m][k]: m = col -> global row gp*8+m, k = quad*8+j within k-step
    // B[k][n]: n = col -> r = rh*32 + rt*16 + n, k = il = quad*8+j
    f32x4 acc0 = {0.f,0.f,0.f,0.f}, acc1 = acc0;
    const float* xrow = x + (gp * 8 + col) * 512 + quad * 8;
    const unsigned short* bbase = b_bf + (rh * 32 + col) * 512 + quad * 8;

    float4 lo = *(const float4*)(xrow);
    float4 hi = *(const float4*)(xrow + 4);
    s16x8 bf0 = *(const s16x8*)(bbase);
    s16x8 bf1 = *(const s16x8*)(bbase + 16 * 512);

    #pragma unroll
    for (int ks = 0; ks < 16; ++ks) {
        float4 nlo, nhi; s16x8 nb0, nb1;
        if (ks < 15) {
            const float* ap = xrow + (ks + 1) * 32;
            nlo = *(const float4*)(ap);
            nhi = *(const float4*)(ap + 4);
            const unsigned short* bp = bbase + (ks + 1) * 32;
            nb0 = *(const s16x8*)(bp);
            nb1 = *(const s16x8*)(bp + 16 * 512);
        } else {
            nlo = lo; nhi = hi; nb0 = bf0; nb1 = bf1;
        }
        s16x8 af;
        af[0] = (short)f2bf(lo.x); af[1] = (short)f2bf(lo.y);
        af[2] = (short)f2bf(lo.z); af[3] = (short)f2bf(lo.w);
        af[4] = (short)f2bf(hi.x); af[5] = (short)f2bf(hi.y);
        af[6] = (short)f2bf(hi.z); af[7] = (short)f2bf(hi.w);
        acc0 = __builtin_amdgcn_mfma_f32_16x16x32_bf16(af, bf0, acc0, 0, 0, 0);
        acc1 = __builtin_amdgcn_mfma_f32_16x16x32_bf16(af, bf1, acc1, 0, 0, 0);
        lo = nlo; hi = nhi; bf0 = nb0; bf1 = nb1;
    }

    // ---------- stage 2: v[lp][oi][r] = sum_ij (S*w1[oi][ij]) * t ----------
    // C layout: lane holds t[row=quad*4+reg][col], row = lp*8+ij.
    // quad pair (0,1) covers lp=0, pair (2,3) covers lp=1; shfl_xor(16)
    // exchanges the complementary 4 ij rows; quad&1 splits the 8 oi outputs.
    {
        const int lp = quad >> 1;
        const int oi_base = (quad & 1) * 4;
        f32x4 accs[2] = {acc0, acc1};
        #pragma unroll
        for (int rt = 0; rt < 2; ++rt) {
            float own[4], oth[4], tij[8];
            own[0] = accs[rt][0]; own[1] = accs[rt][1];
            own[2] = accs[rt][2]; own[3] = accs[rt][3];
            #pragma unroll
            for (int j = 0; j < 4; ++j) oth[j] = __shfl_xor(own[j], 16);
            if ((quad & 1) == 0) {
                #pragma unroll
                for (int j = 0; j < 4; ++j) { tij[j] = own[j]; tij[4 + j] = oth[j]; }
            } else {
                #pragma unroll
                for (int j = 0; j < 4; ++j) { tij[j] = oth[j]; tij[4 + j] = own[j]; }
            }
            #pragma unroll
            for (int oo = 0; oo < 4; ++oo) {
                const int oi = oi_base + oo;
                float v = 0.f;
                #pragma unroll
                for (int j = 0; j < 8; ++j) v += w1_s[oi * 8 + j] * tij[j];
                v_lds[pair][(lp * 8 + oi) * 72 + rh * 32 + rt * 16 + col] = f2bf(v);
            }
        }
    }
    __syncthreads();

    // ---------- stage 3: out_rows[16 x n-half 256] = v[16 x 64] @ a^T ----------
    // A[m][k]: m = col -> v row (lp*8+oi), k = r = half*32 + quad*8 + j
    // B[k][n]: n = col -> ok = nt*16+n, k = r
    const unsigned short* vbase = &v_lds[pair][col * 72 + quad * 8];
    s16x8 va0 = *(const s16x8*)(vbase);
    s16x8 va1 = *(const s16x8*)(vbase + 32);

    const unsigned short* abase = a_bf + col * 64 + quad * 8;
    float* outp = out + gp * 4096;

    #pragma unroll 4
    for (int t = 0; t < 16; ++t) {
        const int nt = rh * 16 + t;
        const unsigned short* apn = abase + nt * (16 * 64);
        s16x8 vb0 = *(const s16x8*)(apn);
        s16x8 vb1 = *(const s16x8*)(apn + 32);
        f32x4 c = {0.f, 0.f, 0.f, 0.f};
        c = __builtin_amdgcn_mfma_f32_16x16x32_bf16(va0, vb0, c, 0, 0, 0);
        c = __builtin_amdgcn_mfma_f32_16x16x32_bf16(va1, vb1, c, 0, 0, 0);
        #pragma unroll
        for (int reg = 0; reg < 4; ++reg) {
            const int row = quad * 4 + reg;            // lp*8 + oi
            outp[(long)(row >> 3) * 4096 + (row & 7) * 512 + nt * 16 + col] = c[reg];
        }
    }
}

extern "C" void kernel_launch(void* const* d_in, const int* in_sizes, int n_in,
                              void* d_out, int out_size, void* d_ws, size_t ws_size,
                              hipStream_t stream) {
    const float* x  = (const float*)d_in[0];  // [4,2048,4096]
    const float* w1 = (const float*)d_in[1];  // [8,8]
    const float* a  = (const float*)d_in[2];  // [512,64]
    const float* b  = (const float*)d_in[3];  // [64,512]

    unsigned short* b_bf = (unsigned short*)d_ws;          // 64 KB
    unsigned short* a_bf = b_bf + 32768;                   // 64 KB
    float*          w1s  = (float*)(a_bf + 32768);         // 256 B

    lokr_pre<<<128, 256, 0, stream>>>(w1, a, b, b_bf, a_bf, w1s);
    lokr_main<<<2048, 256, 0, stream>>>(x, b_bf, a_bf, w1s, (float*)d_out);
}

// Round 3
// 268.116 us; speedup vs baseline: 1.0692x; 1.0692x over previous
//
#include <hip/hip_runtime.h>
#include <hip/hip_bf16.h>

// LoKr: out = x @ kron(w1, a@b).T * S, factored into 3 small GEMMs.
// x view: [65536 A-rows (pos*8+ij) x 512 il], b: [64 r x 512 il],
// a: [512 ok x 64 r], out row (pos*8+oi) x 512 ok  (contiguous since
// pos*4096 + oi*512 = (pos*8+oi)*512).
//
// R2->R3: TA/segment-throughput fix. All x reads are block-cooperative,
// fully coalesced dwordx4 (4 rows x 256B full segments per instr), staged
// via bf16 LDS tile (stride 72 shorts: 16B-aligned ds_read_b128, 2-way
// banks = free). Stage-1 wave owns one 16-r tile -> b-frag loaded once per
// slab, reused over 8 m-frags (16 divergent loads/wave total). Stage-3
// wave owns a 128-wide ok strip; v cached in 64 VGPRs (16 ds_reads), a
// loaded 16x. Divergent-segment instrs drop ~10x per CU.

typedef __attribute__((ext_vector_type(4))) float f32x4;
typedef __attribute__((ext_vector_type(8))) short s16x8;
typedef __attribute__((ext_vector_type(4))) short s16x4;

__device__ inline unsigned short f2bf(float f) {
    unsigned u = __float_as_uint(f);
    u += 0x7FFF + ((u >> 16) & 1);   // round-to-nearest-even
    return (unsigned short)(u >> 16);
}

// Precompute: b -> bf16 [64][512] (row=r, col=il), a -> bf16 [512][64]
// (row=ok, col=r), w1s = w1 * (1/64). Into d_ws (re-poisoned each call).
__global__ void lokr_pre(const float* __restrict__ w1,
                         const float* __restrict__ a,
                         const float* __restrict__ b,
                         unsigned short* __restrict__ b_bf,
                         unsigned short* __restrict__ a_bf,
                         float* __restrict__ w1s) {
    int i = blockIdx.x * 256 + threadIdx.x;
    if (i < 32768) {
        b_bf[i] = f2bf(b[i]);
        a_bf[i] = f2bf(a[i]);
    }
    if (i < 64) w1s[i] = w1[i] * (1.0f / 64.0f);
}

#define LSTR 72   // LDS row stride in shorts (64 + 8 pad)

__global__ __launch_bounds__(256, 4) void lokr_main(
    const float* __restrict__ x,
    const unsigned short* __restrict__ b_bf,
    const unsigned short* __restrict__ a_bf,
    const float* __restrict__ w1s,
    float* __restrict__ out)
{
    // x tile: 128 rows x 64 k (bf16), double buffered. v: 128 rows x 64 r.
    __shared__ __attribute__((aligned(16))) unsigned short xs[2][128 * LSTR];
    __shared__ __attribute__((aligned(16))) unsigned short vs[128 * LSTR];
    __shared__ float w1_s[64];

    const int t    = threadIdx.x;
    const int wave = t >> 6;
    const int lane = t & 63;
    const int col  = lane & 15;   // MFMA: A row / B col / C col
    const int quad = lane >> 4;
    const long rowbase = (long)blockIdx.x * 128;   // A-row base (16 positions)

    if (t < 64) w1_s[t] = w1s[t];

    // Cooperative-load lane mapping: instr i covers rows lrow+i*16, each
    // 16-lane group reads 256B contiguous of one row.
    const int lrow = t >> 4;          // 0..15
    const int lcol = (t & 15) * 4;    // float col within 64-wide slab

    // ---- preload slab 0 ----
    float4 xb[8];
    {
        const float* xg = x + (rowbase + lrow) * 512 + lcol;
        #pragma unroll
        for (int i = 0; i < 8; ++i)
            xb[i] = *(const float4*)(xg + (long)i * 16 * 512);
    }
    #pragma unroll
    for (int i = 0; i < 8; ++i) {
        s16x4 h;
        h[0] = (short)f2bf(xb[i].x); h[1] = (short)f2bf(xb[i].y);
        h[2] = (short)f2bf(xb[i].z); h[3] = (short)f2bf(xb[i].w);
        *(s16x4*)&xs[0][(lrow + i * 16) * LSTR + lcol] = h;
    }
    __syncthreads();

    // ---- stage 1: T[128 x 64r] accumulated; wave owns r-tile = wave*16 ----
    f32x4 acc[8];
    #pragma unroll
    for (int m = 0; m < 8; ++m) acc[m] = (f32x4){0.f, 0.f, 0.f, 0.f};

    const unsigned short* brow = b_bf + (wave * 16 + col) * 512 + quad * 8;

    #pragma unroll 2
    for (int s = 0; s < 8; ++s) {
        // b-frags first (FIFO: their vmcnt wait won't drain x prefetch)
        s16x8 bf0 = *(const s16x8*)(brow + s * 64);
        s16x8 bf1 = *(const s16x8*)(brow + s * 64 + 32);
        // prefetch slab s+1 into registers (coalesced)
        if (s < 7) {
            const float* xg = x + (rowbase + lrow) * 512 + (s + 1) * 64 + lcol;
            #pragma unroll
            for (int i = 0; i < 8; ++i)
                xb[i] = *(const float4*)(xg + (long)i * 16 * 512);
        }
        // MFMA over 8 m-frags from LDS
        const unsigned short* xa = &xs[s & 1][col * LSTR + quad * 8];
        #pragma unroll
        for (int m = 0; m < 8; ++m) {
            s16x8 a0 = *(const s16x8*)(xa + m * 16 * LSTR);
            s16x8 a1 = *(const s16x8*)(xa + m * 16 * LSTR + 32);
            acc[m] = __builtin_amdgcn_mfma_f32_16x16x32_bf16(a0, bf0, acc[m], 0, 0, 0);
            acc[m] = __builtin_amdgcn_mfma_f32_16x16x32_bf16(a1, bf1, acc[m], 0, 0, 0);
        }
        // stage slab s+1 into the other buffer
        if (s < 7) {
            #pragma unroll
            for (int i = 0; i < 8; ++i) {
                s16x4 h;
                h[0] = (short)f2bf(xb[i].x); h[1] = (short)f2bf(xb[i].y);
                h[2] = (short)f2bf(xb[i].z); h[3] = (short)f2bf(xb[i].w);
                *(s16x4*)&xs[(s + 1) & 1][(lrow + i * 16) * LSTR + lcol] = h;
            }
        }
        __syncthreads();
    }

    // ---- stage 2: mix ij->oi with w1, write v (bf16) to LDS ----
    // acc[m] C-layout: T row = m*16 + quad*4 + reg, r = wave*16 + col.
    // quads (0,1) hold position 2m, quads (2,3) hold 2m+1; shfl_xor(16)
    // exchanges complementary ij rows; quad&1 splits the 8 oi outputs.
    #pragma unroll
    for (int m = 0; m < 8; ++m) {
        float own[4], oth[4], tij[8];
        #pragma unroll
        for (int j = 0; j < 4; ++j) own[j] = acc[m][j];
        #pragma unroll
        for (int j = 0; j < 4; ++j) oth[j] = __shfl_xor(own[j], 16);
        if ((quad & 1) == 0) {
            #pragma unroll
            for (int j = 0; j < 4; ++j) { tij[j] = own[j]; tij[4 + j] = oth[j]; }
        } else {
            #pragma unroll
            for (int j = 0; j < 4; ++j) { tij[j] = oth[j]; tij[4 + j] = own[j]; }
        }
        const int plocal = m * 2 + (quad >> 1);
        const int oib = (quad & 1) * 4;
        #pragma unroll
        for (int oo = 0; oo < 4; ++oo) {
            float v = 0.f;
            #pragma unroll
            for (int j = 0; j < 8; ++j) v += w1_s[(oib + oo) * 8 + j] * tij[j];
            vs[(plocal * 8 + oib + oo) * LSTR + wave * 16 + col] = f2bf(v);
        }
    }
    __syncthreads();

    // ---- stage 3: out[128 x 512] = v[128 x 64] @ a^T; wave owns ok strip ----
    // v cached in regs: va[m] covers k 0..31 / 32..63 for A-row m*16+col.
    s16x8 va0[8], va1[8];
    #pragma unroll
    for (int m = 0; m < 8; ++m) {
        const unsigned short* vp = &vs[(m * 16 + col) * LSTR + quad * 8];
        va0[m] = *(const s16x8*)(vp);
        va1[m] = *(const s16x8*)(vp + 32);
    }

    const unsigned short* ab = a_bf + (wave * 128 + col) * 64 + quad * 8;
    float* ob = out + (long)blockIdx.x * 65536 + wave * 128 + col;

    for (int nt = 0; nt < 8; ++nt) {
        s16x8 af0 = *(const s16x8*)(ab + nt * 16 * 64);
        s16x8 af1 = *(const s16x8*)(ab + nt * 16 * 64 + 32);
        #pragma unroll
        for (int m = 0; m < 8; ++m) {
            f32x4 c = {0.f, 0.f, 0.f, 0.f};
            c = __builtin_amdgcn_mfma_f32_16x16x32_bf16(va0[m], af0, c, 0, 0, 0);
            c = __builtin_amdgcn_mfma_f32_16x16x32_bf16(va1[m], af1, c, 0, 0, 0);
            #pragma unroll
            for (int reg = 0; reg < 4; ++reg) {
                const int rl = m * 16 + quad * 4 + reg;   // plocal*8 + oi
                ob[(long)rl * 512 + nt * 16] = c[reg];
            }
        }
    }
}

extern "C" void kernel_launch(void* const* d_in, const int* in_sizes, int n_in,
                              void* d_out, int out_size, void* d_ws, size_t ws_size,
                              hipStream_t stream) {
    const float* x  = (const float*)d_in[0];  // [4,2048,4096]
    const float* w1 = (const float*)d_in[1];  // [8,8]
    const float* a  = (const float*)d_in[2];  // [512,64]
    const float* b  = (const float*)d_in[3];  // [64,512]

    unsigned short* b_bf = (unsigned short*)d_ws;          // 64 KB
    unsigned short* a_bf = b_bf + 32768;                   // 64 KB
    float*          w1s  = (float*)(a_bf + 32768);         // 256 B

    lokr_pre<<<128, 256, 0, stream>>>(w1, a, b, b_bf, a_bf, w1s);
    lokr_main<<<512, 256, 0, stream>>>(x, b_bf, a_bf, w1s, (float*)d_out);
}